// Round 1
// 123.494 us; speedup vs baseline: 1.0015x; 1.0015x over previous
//
#include <hip/hip_runtime.h>
#include <hip/hip_bf16.h>

typedef unsigned short u16;
typedef unsigned int u32;
typedef __bf16 bf16x8 __attribute__((ext_vector_type(8)));
typedef u16 u16x8 __attribute__((ext_vector_type(8)));
typedef float floatx4 __attribute__((ext_vector_type(4)));

#define T_SEQ 2048
#define HDIM 64
#define NBH 32   // B*H

static __device__ __forceinline__ u16 f2b_rne(float x) {
    union { float f; u32 u; } c; c.f = x;
    u32 u = c.u;
    return (u16)((u + 0x7fffu + ((u >> 16) & 1u)) >> 16);
}
static __device__ __forceinline__ u16 f2b_trunc(float x) {
    union { float f; u32 u; } c; c.f = x;
    return (u16)(c.u >> 16);
}

// async 16B/lane global->LDS; LDS dest = wave-uniform base + lane*16
#define GLOAD_LDS16(gp, lp)                                                      \
    __builtin_amdgcn_global_load_lds(                                            \
        (const __attribute__((address_space(1))) u32*)(gp),                      \
        (__attribute__((address_space(3))) u32*)(lp), 16, 0, 0)

// ---- prepass: K fp32->bf16 flat; V fp32->bf16 transposed [BH,D,T] with
// column permutation pos(k) = tp*32 + qg*8 + u*4 + j  (tp=k>>5, u=(k>>4)&1,
// qg=(k>>2)&3, j=k&3, within each 64-key window) so the 16x16x32 PV B-frag
// (lane quad, elems e=0..7 -> k=quad*8+e) is one contiguous 16B LDS read at
// pos = tp*32 + quad*8. ----
__global__ __launch_bounds__(256) void prep(const float* __restrict__ k,
                                            const float* __restrict__ v,
                                            u16* __restrict__ kb,
                                            u16* __restrict__ vt) {
    __shared__ u16 tile[64][68];
    const int bh = blockIdx.y, t0 = blockIdx.x * 64;
    const int tid = threadIdx.x;

    const float* ksrc = k + ((size_t)bh * T_SEQ + t0) * HDIM;
    u16* kdst = kb + ((size_t)bh * T_SEQ + t0) * HDIM;
#pragma unroll
    for (int p = 0; p < 4; p++) {
        int idx = p * 256 + tid;
        float4 f = ((const float4*)ksrc)[idx];
        ushort4 o;
        o.x = f2b_rne(f.x); o.y = f2b_rne(f.y); o.z = f2b_rne(f.z); o.w = f2b_rne(f.w);
        ((ushort4*)kdst)[idx] = o;
    }

    const float* vsrc = v + ((size_t)bh * T_SEQ + t0) * HDIM;
#pragma unroll
    for (int p = 0; p < 4; p++) {
        int idx = p * 256 + tid;
        int r = idx >> 4, c4 = (idx & 15) * 4;
        float4 f = *(const float4*)(vsrc + r * HDIM + c4);
        tile[c4 + 0][r] = f2b_rne(f.x);
        tile[c4 + 1][r] = f2b_rne(f.y);
        tile[c4 + 2][r] = f2b_rne(f.z);
        tile[c4 + 3][r] = f2b_rne(f.w);
    }
    __syncthreads();
    // 16B stores: pos block pb (8 u16) = keys {tp*32+qg*4+j} u {tp*32+16+qg*4+j}
    u16* dst = vt + (size_t)bh * HDIM * T_SEQ + t0;
#pragma unroll
    for (int p = 0; p < 2; p++) {
        int idx = p * 256 + tid;
        int d = idx >> 3, pb = idx & 7;
        int k0 = (pb >> 2) * 32 + (pb & 3) * 4;
        union { u16x8 v8; ushort4 q[2]; } w;
        w.q[0] = *(ushort4*)&tile[d][k0];
        w.q[1] = *(ushort4*)&tile[d][k0 + 16];
        *(u16x8*)(dst + (size_t)d * T_SEQ + pb * 8) = w.v8;
    }
}

// ---- main kernel ----
// grid (bh=32, s=16), 512 threads / 8 waves. Each block owns a PAIR of
// q-tiles (qtHi=31-pr, qtLo=pr): waves 0-3 -> hi rows, waves 4-7 -> lo rows.
// Both tiles share K/V staging: stages per block = qtHi+1, tile-computes = 33
// (uniform) -> no occupancy tail. pr cousin map keeps per-CU stage sums = 49.
// S^T = K.Q^T so the QK^T C-frag IS the 16x16x32 PV A-frag (k = quad*8+e,
// key = (e>>2)*16 + quad*4 + (e&3) within 32-chunk — matched by prep's V perm).
__global__ __launch_bounds__(512, 4) void fattn(const float* __restrict__ q,
                                                const u16* __restrict__ kb,
                                                const u16* __restrict__ vtb,
                                                float* __restrict__ out) {
    __shared__ __align__(16) u16 Kl[2][64 * 64];   // [key][d], XOR slot swizzle
    __shared__ __align__(16) u16 Vl[2][64 * 64];   // [d][perm-key], +d slot swizzle

    const int bh = blockIdx.x;
    const int s = blockIdx.y;                      // 0..15
    const int pr = (s & 8) ? (s ^ 7) : s;          // bijective, cousin-balanced
    const int qtHi = 31 - pr, qtLo = pr;

    const int tid = threadIdx.x;
    const int wave = tid >> 6, lane = tid & 63;
    const int l15 = lane & 15, quad = lane >> 4;
    const int qt = (wave < 4) ? qtHi : qtLo;       // this wave's q-tile
    const int wrow = (wave & 3) * 16;
    const int qrow_base = qt * 64 + wrow;

    const float* qp = q + (size_t)bh * T_SEQ * HDIM;
    const u16* kp = kb + (size_t)bh * T_SEQ * HDIM;
    const u16* vp = vtb + (size_t)bh * HDIM * T_SEQ;

    // staging: 8 waves cover the full 64-row K tile and 64-row V^T tile,
    // one 16B GLOAD each. lane covers LDS bytes [wave*1024 + lane*16]
    // = row (wave*8 + (lane>>3)), slot (lane&7). Source picked so that
    // LDS slot b at row r holds: K block b^(r&7); V perm-slot (b-r)&7.
    const int srow = wave * 8 + (lane >> 3);
    const int slot = lane & 7;
    const u16* kg0 = kp + srow * HDIM + (slot ^ (srow & 7)) * 8;
    const u16* vg0 = vp + (size_t)srow * T_SEQ + ((slot - srow) & 7) * 8;

    auto stage = [&](int j, int buf) {
        GLOAD_LDS16(kg0 + j * 64 * HDIM, &Kl[buf][wave * 512]);
        GLOAD_LDS16(vg0 + j * 64, &Vl[buf][wave * 512]);
    };

    stage(0, 0);   // prologue: tile 0 -> buffer 0 (async)

    // Q fragments (B-layout): lane l15 holds Q[row][kc*32+quad*8..+7],
    // pre-scaled by scale*log2(e)
    const float SL2E = 0.125f * 1.44269504088896f;
    bf16x8 qf[2];
    {
        const float* qrow = qp + (size_t)(qrow_base + l15) * HDIM;
#pragma unroll
        for (int kc = 0; kc < 2; kc++) {
            const float4* p4 = (const float4*)(qrow + kc * 32 + quad * 8);
            float4 fa = p4[0], fb = p4[1];
            union { bf16x8 v; u16 s[8]; } cv;
            cv.s[0] = f2b_rne(fa.x * SL2E); cv.s[1] = f2b_rne(fa.y * SL2E);
            cv.s[2] = f2b_rne(fa.z * SL2E); cv.s[3] = f2b_rne(fa.w * SL2E);
            cv.s[4] = f2b_rne(fb.x * SL2E); cv.s[5] = f2b_rne(fb.y * SL2E);
            cv.s[6] = f2b_rne(fb.z * SL2E); cv.s[7] = f2b_rne(fb.w * SL2E);
            qf[kc] = cv.v;
        }
    }

    floatx4 o_acc[4];
#pragma unroll
    for (int dt = 0; dt < 4; dt++) o_acc[dt] = (floatx4){0.f, 0.f, 0.f, 0.f};
    float ls0 = 0.f, ls1 = 0.f;                    // partial row-sums, qrow = l15

    for (int j = 0; j <= qtHi; ++j) {
        const int cur = j & 1;
        __syncthreads();   // vmcnt drain + barrier: buf[cur] fully staged

        if (j < qtHi) stage(j + 1, cur ^ 1);       // async prefetch, no wait
        if (j > qt) continue;                      // wave-uniform: lo-waves done

        // S^T = K . Q^T : A = K-frag (m=key), B = qf (n=qrow)
        floatx4 sacc[4];
#pragma unroll
        for (int t = 0; t < 4; t++) sacc[t] = (floatx4){0.f, 0.f, 0.f, 0.f};
        const u16* Kc = Kl[cur];
#pragma unroll
        for (int kc = 0; kc < 2; kc++) {
#pragma unroll
            for (int t = 0; t < 4; t++) {
                int rk = t * 16 + l15;
                bf16x8 kf = *(const bf16x8*)(Kc + rk * 64 + ((kc * 4 + quad) ^ (rk & 7)) * 8);
                sacc[t] = __builtin_amdgcn_mfma_f32_16x16x32_bf16(kf, qf[kc], sacc[t], 0, 0, 0);
            }
        }

        // P^T = exp2(S^T), causal mask on diagonal tile, pack straight into
        // the two 16x16x32 PV A-frags (e = (t&1)*4 + rg within chunk t>>1)
        union { bf16x8 v; u16 h[8]; } pk[2];
        const bool diag = (j == qt);
        const int gq = wrow + l15;                 // q-row within 64-block
#pragma unroll
        for (int t = 0; t < 4; t++) {
#pragma unroll
            for (int rg = 0; rg < 4; rg++) {
                float e = __builtin_amdgcn_exp2f(sacc[t][rg]);
                if (diag && (t * 16 + quad * 4 + rg > gq)) e = 0.f;
                if (t < 2) ls0 += e; else ls1 += e;
                pk[t >> 1].h[(t & 1) * 4 + rg] = f2b_trunc(e);
            }
        }

        // O += P . V : one 16x16x32 per (32-key chunk, d-tile)
        const u16* Vc = Vl[cur];
#pragma unroll
        for (int tp = 0; tp < 2; tp++) {
#pragma unroll
            for (int dt = 0; dt < 4; dt++) {
                int d = dt * 16 + l15;
                int sl = (tp * 4 + quad + d) & 7;
                bf16x8 vf = *(const bf16x8*)(Vc + d * 64 + sl * 8);
                o_acc[dt] = __builtin_amdgcn_mfma_f32_16x16x32_bf16(pk[tp].v, vf, o_acc[dt], 0, 0, 0);
            }
        }
    }

    // epilogue: reduce lsum over quads, redistribute, store O/l
    float tot = ls0 + ls1;
    tot += __shfl_xor(tot, 16, 64);
    tot += __shfl_xor(tot, 32, 64);                // lane holds sum for qrow=l15
    float* op = out + (size_t)bh * T_SEQ * HDIM;
#pragma unroll
    for (int rg = 0; rg < 4; rg++) {
        float inv = 1.0f / __shfl(tot, quad * 4 + rg, 64);
        size_t row = (size_t)(qrow_base + quad * 4 + rg) * HDIM;
#pragma unroll
        for (int dt = 0; dt < 4; dt++)
            op[row + dt * 16 + l15] = o_acc[dt][rg] * inv;
    }
}

extern "C" void kernel_launch(void* const* d_in, const int* in_sizes, int n_in,
                              void* d_out, int out_size, void* d_ws, size_t ws_size,
                              hipStream_t stream) {
    const float* q = (const float*)d_in[0];
    const float* k = (const float*)d_in[1];
    const float* v = (const float*)d_in[2];
    float* out = (float*)d_out;

    u16* kb = (u16*)d_ws;                               // 8 MB bf16 K
    u16* vt = kb + (size_t)NBH * T_SEQ * HDIM;          // 8 MB bf16 V^T (permuted)

    prep<<<dim3(T_SEQ / 64, NBH), 256, 0, stream>>>(k, v, kb, vt);
    fattn<<<dim3(NBH, 16), 512, 0, stream>>>(q, kb, vt, out);
}

// Round 2
// 123.050 us; speedup vs baseline: 1.0051x; 1.0036x over previous
//
#include <hip/hip_runtime.h>
#include <hip/hip_bf16.h>

typedef unsigned short u16;
typedef unsigned int u32;
typedef __bf16 bf16x8 __attribute__((ext_vector_type(8)));
typedef u16 u16x8 __attribute__((ext_vector_type(8)));
typedef float floatx4 __attribute__((ext_vector_type(4)));

#define T_SEQ 2048
#define HDIM 64
#define NBH 32   // B*H

static __device__ __forceinline__ u16 f2b_rne(float x) {
    union { float f; u32 u; } c; c.f = x;
    u32 u = c.u;
    return (u16)((u + 0x7fffu + ((u >> 16) & 1u)) >> 16);
}
static __device__ __forceinline__ u16 f2b_trunc(float x) {
    union { float f; u32 u; } c; c.f = x;
    return (u16)(c.u >> 16);
}

// async 16B/lane global->LDS; LDS dest = wave-uniform base + lane*16
#define GLOAD_LDS16(gp, lp)                                                      \
    __builtin_amdgcn_global_load_lds(                                            \
        (const __attribute__((address_space(1))) u32*)(gp),                      \
        (__attribute__((address_space(3))) u32*)(lp), 16, 0, 0)

// counted vmem waits (wait until <= N vmem ops outstanding), memory-fenced so
// no LDS read/write crosses them
#define WAIT_VM(N) asm volatile("s_waitcnt vmcnt(" #N ")" ::: "memory")

// ---- prepass: K fp32->bf16 flat; V fp32->bf16 transposed [BH,D,T] with
// column permutation pos(k) = tp*32 + qg*8 + u*4 + j  (tp=k>>5, u=(k>>4)&1,
// qg=(k>>2)&3, j=k&3, within each 64-key window) so the 16x16x32 PV B-frag
// (lane quad, elems e=0..7 -> k=quad*8+e) is one contiguous 16B LDS read at
// pos = tp*32 + quad*8. ----
__global__ __launch_bounds__(256) void prep(const float* __restrict__ k,
                                            const float* __restrict__ v,
                                            u16* __restrict__ kb,
                                            u16* __restrict__ vt) {
    __shared__ u16 tile[64][68];
    const int bh = blockIdx.y, t0 = blockIdx.x * 64;
    const int tid = threadIdx.x;

    const float* ksrc = k + ((size_t)bh * T_SEQ + t0) * HDIM;
    u16* kdst = kb + ((size_t)bh * T_SEQ + t0) * HDIM;
#pragma unroll
    for (int p = 0; p < 4; p++) {
        int idx = p * 256 + tid;
        float4 f = ((const float4*)ksrc)[idx];
        ushort4 o;
        o.x = f2b_rne(f.x); o.y = f2b_rne(f.y); o.z = f2b_rne(f.z); o.w = f2b_rne(f.w);
        ((ushort4*)kdst)[idx] = o;
    }

    const float* vsrc = v + ((size_t)bh * T_SEQ + t0) * HDIM;
#pragma unroll
    for (int p = 0; p < 4; p++) {
        int idx = p * 256 + tid;
        int r = idx >> 4, c4 = (idx & 15) * 4;
        float4 f = *(const float4*)(vsrc + r * HDIM + c4);
        tile[c4 + 0][r] = f2b_rne(f.x);
        tile[c4 + 1][r] = f2b_rne(f.y);
        tile[c4 + 2][r] = f2b_rne(f.z);
        tile[c4 + 3][r] = f2b_rne(f.w);
    }
    __syncthreads();
    // 16B stores: pos block pb (8 u16) = keys {tp*32+qg*4+j} u {tp*32+16+qg*4+j}
    u16* dst = vt + (size_t)bh * HDIM * T_SEQ + t0;
#pragma unroll
    for (int p = 0; p < 2; p++) {
        int idx = p * 256 + tid;
        int d = idx >> 3, pb = idx & 7;
        int k0 = (pb >> 2) * 32 + (pb & 3) * 4;
        union { u16x8 v8; ushort4 q[2]; } w;
        w.q[0] = *(ushort4*)&tile[d][k0];
        w.q[1] = *(ushort4*)&tile[d][k0 + 16];
        *(u16x8*)(dst + (size_t)d * T_SEQ + pb * 8) = w.v8;
    }
}

// ---- main kernel ----
// 1-D grid of 512, 512 threads / 8 waves. Decode: xcd=id&7 so each XCD sees
// only 4 distinct bh (2MB K/V working set -> L2-resident). Each block owns a
// PAIR of q-tiles (qtHi=31-pr, qtLo=pr): waves 0-3 -> hi rows, waves 4-7 ->
// lo rows; stages per block = qtHi+1, tile-computes = 33 (uniform).
// 4-deep LDS pipeline: raw s_barrier + counted vmcnt (steady state vmcnt(4):
// tiles j+1,j+2 in flight across the barrier, tile j+3 staged after it) so
// global->LDS latency is hidden behind ~3 compute phases instead of drained
// every iteration (the old __syncthreads vmcnt(0) drain was the bottleneck:
// MfmaUtil 15%, VALUBusy 27%, HBM 10% -- nothing saturated).
// S^T = K.Q^T so the QK^T C-frag IS the 16x16x32 PV A-frag.
__global__ __launch_bounds__(512, 4) void fattn(const float* __restrict__ q,
                                                const u16* __restrict__ kb,
                                                const u16* __restrict__ vtb,
                                                float* __restrict__ out) {
    __shared__ __align__(16) u16 Kl[4][64 * 64];   // [key][d], XOR slot swizzle
    __shared__ __align__(16) u16 Vl[4][64 * 64];   // [d][perm-key], +d slot swizzle

    const int id = blockIdx.x;
    const int xcd = id & 7;
    const int u = id >> 3;                         // 0..63
    const int bh = xcd * 4 + (u & 3);              // 4 bh per XCD
    const int s = u >> 2;                          // 0..15; s = id>>5
    const int pr = (s & 8) ? (s ^ 7) : s;          // cousin map: CU pairs (s,15-s)
    const int qtHi = 31 - pr, qtLo = pr;

    const int tid = threadIdx.x;
    const int wave = tid >> 6, lane = tid & 63;
    const int l15 = lane & 15, quad = lane >> 4;
    const int qt = (wave < 4) ? qtHi : qtLo;       // this wave's q-tile
    const int wrow = (wave & 3) * 16;
    const int qrow_base = qt * 64 + wrow;

    const float* qp = q + (size_t)bh * T_SEQ * HDIM;
    const u16* kp = kb + (size_t)bh * T_SEQ * HDIM;
    const u16* vp = vtb + (size_t)bh * HDIM * T_SEQ;

    // staging: 8 waves cover the full 64-row K tile and 64-row V^T tile,
    // one 16B GLOAD each (2 vmem ops per wave per tile). lane covers LDS
    // bytes [wave*1024 + lane*16] = row (wave*8 + (lane>>3)), slot (lane&7).
    // Source picked so LDS slot b at row r holds: K block b^(r&7);
    // V perm-slot (b-r)&7.
    const int srow = wave * 8 + (lane >> 3);
    const int slot = lane & 7;
    const u16* kg0 = kp + srow * HDIM + (slot ^ (srow & 7)) * 8;
    const u16* vg0 = vp + (size_t)srow * T_SEQ + ((slot - srow) & 7) * 8;

    auto stage = [&](int j, int buf) {
        GLOAD_LDS16(kg0 + j * 64 * HDIM, &Kl[buf][wave * 512]);
        GLOAD_LDS16(vg0 + j * 64, &Vl[buf][wave * 512]);
    };

    // Q fragments (B-layout): lane l15 holds Q[row][kc*32+quad*8..+7],
    // pre-scaled by scale*log2(e). Loaded BEFORE the pipeline prologue so the
    // compiler's wait for Q data doesn't drain the staged tiles.
    const float SL2E = 0.125f * 1.44269504088896f;
    bf16x8 qf[2];
    {
        const float* qrow = qp + (size_t)(qrow_base + l15) * HDIM;
#pragma unroll
        for (int kc = 0; kc < 2; kc++) {
            const float4* p4 = (const float4*)(qrow + kc * 32 + quad * 8);
            float4 fa = p4[0], fb = p4[1];
            union { bf16x8 v; u16 s[8]; } cv;
            cv.s[0] = f2b_rne(fa.x * SL2E); cv.s[1] = f2b_rne(fa.y * SL2E);
            cv.s[2] = f2b_rne(fa.z * SL2E); cv.s[3] = f2b_rne(fa.w * SL2E);
            cv.s[4] = f2b_rne(fb.x * SL2E); cv.s[5] = f2b_rne(fb.y * SL2E);
            cv.s[6] = f2b_rne(fb.z * SL2E); cv.s[7] = f2b_rne(fb.w * SL2E);
            qf[kc] = cv.v;
        }
    }

    // pipeline prologue: 3 tiles in flight (qtHi >= 16 always, so all valid)
    stage(0, 0);
    stage(1, 1);
    stage(2, 2);

    floatx4 o_acc[4];
#pragma unroll
    for (int dt = 0; dt < 4; dt++) o_acc[dt] = (floatx4){0.f, 0.f, 0.f, 0.f};
    float ls0 = 0.f, ls1 = 0.f;                    // partial row-sums, qrow = l15

    for (int j = 0; j <= qtHi; ++j) {
        // wait for tile j's 2 loads (per wave), leaving later tiles in flight;
        // branches are block-uniform (qtHi uniform)
        if (j + 2 <= qtHi)      WAIT_VM(4);
        else if (j + 1 <= qtHi) WAIT_VM(2);
        else                    WAIT_VM(0);
        __builtin_amdgcn_s_barrier();              // all waves' tile-j data in LDS

        if (j + 3 <= qtHi) stage(j + 3, (j + 3) & 3);  // async, 3 ahead
        if (j > qt) continue;                      // wave-uniform: lo-waves done

        const int cur = j & 3;

        // S^T = K . Q^T : A = K-frag (m=key), B = qf (n=qrow)
        floatx4 sacc[4];
#pragma unroll
        for (int t = 0; t < 4; t++) sacc[t] = (floatx4){0.f, 0.f, 0.f, 0.f};
        const u16* Kc = Kl[cur];
        __builtin_amdgcn_s_setprio(1);
#pragma unroll
        for (int kc = 0; kc < 2; kc++) {
#pragma unroll
            for (int t = 0; t < 4; t++) {
                int rk = t * 16 + l15;
                bf16x8 kf = *(const bf16x8*)(Kc + rk * 64 + ((kc * 4 + quad) ^ (rk & 7)) * 8);
                sacc[t] = __builtin_amdgcn_mfma_f32_16x16x32_bf16(kf, qf[kc], sacc[t], 0, 0, 0);
            }
        }
        __builtin_amdgcn_s_setprio(0);

        // P^T = exp2(S^T), causal mask on diagonal tile, pack straight into
        // the two 16x16x32 PV A-frags (e = (t&1)*4 + rg within chunk t>>1)
        union { bf16x8 v; u16 h[8]; } pk[2];
        const bool diag = (j == qt);
        const int gq = wrow + l15;                 // q-row within 64-block
#pragma unroll
        for (int t = 0; t < 4; t++) {
#pragma unroll
            for (int rg = 0; rg < 4; rg++) {
                float e = __builtin_amdgcn_exp2f(sacc[t][rg]);
                if (diag && (t * 16 + quad * 4 + rg > gq)) e = 0.f;
                if (t < 2) ls0 += e; else ls1 += e;
                pk[t >> 1].h[(t & 1) * 4 + rg] = f2b_trunc(e);
            }
        }

        // O += P . V : one 16x16x32 per (32-key chunk, d-tile)
        const u16* Vc = Vl[cur];
        __builtin_amdgcn_s_setprio(1);
#pragma unroll
        for (int tp = 0; tp < 2; tp++) {
#pragma unroll
            for (int dt = 0; dt < 4; dt++) {
                int d = dt * 16 + l15;
                int sl = (tp * 4 + quad + d) & 7;
                bf16x8 vf = *(const bf16x8*)(Vc + d * 64 + sl * 8);
                o_acc[dt] = __builtin_amdgcn_mfma_f32_16x16x32_bf16(pk[tp].v, vf, o_acc[dt], 0, 0, 0);
            }
        }
        __builtin_amdgcn_s_setprio(0);
    }

    // epilogue: reduce lsum over quads, redistribute, store O/l
    float tot = ls0 + ls1;
    tot += __shfl_xor(tot, 16, 64);
    tot += __shfl_xor(tot, 32, 64);                // lane holds sum for qrow=l15
    float* op = out + (size_t)bh * T_SEQ * HDIM;
#pragma unroll
    for (int rg = 0; rg < 4; rg++) {
        float inv = 1.0f / __shfl(tot, quad * 4 + rg, 64);
        size_t row = (size_t)(qrow_base + quad * 4 + rg) * HDIM;
#pragma unroll
        for (int dt = 0; dt < 4; dt++)
            op[row + dt * 16 + l15] = o_acc[dt][rg] * inv;
    }
}

extern "C" void kernel_launch(void* const* d_in, const int* in_sizes, int n_in,
                              void* d_out, int out_size, void* d_ws, size_t ws_size,
                              hipStream_t stream) {
    const float* q = (const float*)d_in[0];
    const float* k = (const float*)d_in[1];
    const float* v = (const float*)d_in[2];
    float* out = (float*)d_out;

    u16* kb = (u16*)d_ws;                               // 8 MB bf16 K
    u16* vt = kb + (size_t)NBH * T_SEQ * HDIM;          // 8 MB bf16 V^T (permuted)

    prep<<<dim3(T_SEQ / 64, NBH), 256, 0, stream>>>(k, v, kb, vt);
    fattn<<<dim3(512), 512, 0, stream>>>(q, kb, vt, out);
}

// Round 3
// 119.497 us; speedup vs baseline: 1.0350x; 1.0297x over previous
//
#include <hip/hip_runtime.h>
#include <hip/hip_bf16.h>

typedef unsigned short u16;
typedef unsigned int u32;
typedef __bf16 bf16x8 __attribute__((ext_vector_type(8)));
typedef u16 u16x8 __attribute__((ext_vector_type(8)));
typedef float floatx4 __attribute__((ext_vector_type(4)));

#define T_SEQ 2048
#define HDIM 64
#define NBH 32   // B*H

static __device__ __forceinline__ u16 f2b_rne(float x) {
    union { float f; u32 u; } c; c.f = x;
    u32 u = c.u;
    return (u16)((u + 0x7fffu + ((u >> 16) & 1u)) >> 16);
}
static __device__ __forceinline__ u16 f2b_trunc(float x) {
    union { float f; u32 u; } c; c.f = x;
    return (u16)(c.u >> 16);
}

// async 16B/lane global->LDS; LDS dest = wave-uniform base + lane*16
#define GLOAD_LDS16(gp, lp)                                                      \
    __builtin_amdgcn_global_load_lds(                                            \
        (const __attribute__((address_space(1))) u32*)(gp),                      \
        (__attribute__((address_space(3))) u32*)(lp), 16, 0, 0)

// counted vmem waits (wait until <= N vmem ops outstanding)
#define WAIT_VM(N) asm volatile("s_waitcnt vmcnt(" #N ")" ::: "memory")

// ---- prepass: K fp32->bf16 flat; V fp32->bf16 transposed [BH,D,T] with
// column permutation pos(k) = tp*32 + qg*8 + u*4 + j  (tp=k>>5, u=(k>>4)&1,
// qg=(k>>2)&3, j=k&3, within each 64-key window) so the 16x16x32 PV B-frag
// (lane quad, elems e=0..7 -> k=quad*8+e) is one contiguous 16B LDS read at
// pos = tp*32 + quad*8. Chunk-preserving: keys 0-31 -> pos 0-31. ----
__global__ __launch_bounds__(256) void prep(const float* __restrict__ k,
                                            const float* __restrict__ v,
                                            u16* __restrict__ kb,
                                            u16* __restrict__ vt) {
    __shared__ u16 tile[64][68];
    const int bh = blockIdx.y, t0 = blockIdx.x * 64;
    const int tid = threadIdx.x;

    const float* ksrc = k + ((size_t)bh * T_SEQ + t0) * HDIM;
    u16* kdst = kb + ((size_t)bh * T_SEQ + t0) * HDIM;
#pragma unroll
    for (int p = 0; p < 4; p++) {
        int idx = p * 256 + tid;
        float4 f = ((const float4*)ksrc)[idx];
        ushort4 o;
        o.x = f2b_rne(f.x); o.y = f2b_rne(f.y); o.z = f2b_rne(f.z); o.w = f2b_rne(f.w);
        ((ushort4*)kdst)[idx] = o;
    }

    const float* vsrc = v + ((size_t)bh * T_SEQ + t0) * HDIM;
#pragma unroll
    for (int p = 0; p < 4; p++) {
        int idx = p * 256 + tid;
        int r = idx >> 4, c4 = (idx & 15) * 4;
        float4 f = *(const float4*)(vsrc + r * HDIM + c4);
        tile[c4 + 0][r] = f2b_rne(f.x);
        tile[c4 + 1][r] = f2b_rne(f.y);
        tile[c4 + 2][r] = f2b_rne(f.z);
        tile[c4 + 3][r] = f2b_rne(f.w);
    }
    __syncthreads();
    // 16B stores: pos block pb (8 u16) = keys {tp*32+qg*4+j} u {tp*32+16+qg*4+j}
    u16* dst = vt + (size_t)bh * HDIM * T_SEQ + t0;
#pragma unroll
    for (int p = 0; p < 2; p++) {
        int idx = p * 256 + tid;
        int d = idx >> 3, pb = idx & 7;
        int k0 = (pb >> 2) * 32 + (pb & 3) * 4;
        union { u16x8 v8; ushort4 q[2]; } w;
        w.q[0] = *(ushort4*)&tile[d][k0];
        w.q[1] = *(ushort4*)&tile[d][k0 + 16];
        *(u16x8*)(dst + (size_t)d * T_SEQ + pb * 8) = w.v8;
    }
}

// ---- main kernel ----
// 1-D grid of 512, 512 threads / 8 waves. Decode: xcd=id&7 -> 4 distinct bh
// per XCD (2MB K/V, L2-resident). Block owns q-tile pair (qtHi=31-pr, qtLo=pr).
// KEY-SPLIT: wave = (tile=wave>>2, qhalf=(wave>>1)&1, khalf=wave&1). Each wave
// computes a 32q x 32key quadrant, reading only ITS 4KB of K and 4KB of V per
// iteration (was 16KB/wave: 4 waves redundantly read the same tile). LDS-read
// per CU drops 4.2MB->2.1MB -- LDS BW was the invariant wall across rounds 0-2
// (MfmaUtil 15%, VALUBusy 27%, time pinned at 42.7us regardless of pipelining).
// Partial O (32q x 64d) per wave; khalf pairs reduce via LDS in the epilogue.
// Row-sums via MFMA against all-ones B (off the VALU chain, and positioned
// exactly as o_acc rows -> no shuffles to normalize).
__global__ __launch_bounds__(512, 4) void fattn(const float* __restrict__ q,
                                                const u16* __restrict__ kb,
                                                const u16* __restrict__ vtb,
                                                float* __restrict__ out) {
    __shared__ __align__(16) u16 Kl[4][64 * 64];   // [key][d], XOR slot swizzle
    __shared__ __align__(16) u16 Vl[4][64 * 64];   // [d][perm-key], +d slot swizzle

    const int id = blockIdx.x;
    const int xcd = id & 7;
    const int u = id >> 3;                         // 0..63
    const int bh = xcd * 4 + (u & 3);              // 4 bh per XCD
    const int s = u >> 2;                          // 0..15
    const int pr = (s & 8) ? (s ^ 7) : s;          // cousin map: CU pairs (s,15-s)
    const int qtHi = 31 - pr, qtLo = pr;

    const int tid = threadIdx.x;
    const int wave = tid >> 6, lane = tid & 63;
    const int l15 = lane & 15, quad = lane >> 4;
    const int tile_sel = wave >> 2;                // 0: hi tile, 1: lo tile
    const int qhalf = (wave >> 1) & 1;             // which 32 q-rows
    const int khalf = wave & 1;                    // which 32 keys
    const int qt = tile_sel ? qtLo : qtHi;
    const int qrow_base = qt * 64 + qhalf * 32;

    const float* qp = q + (size_t)bh * T_SEQ * HDIM;
    const u16* kp = kb + (size_t)bh * T_SEQ * HDIM;
    const u16* vp = vtb + (size_t)bh * HDIM * T_SEQ;

    // staging: 8 waves cover the 64-row K tile + 64-row V^T tile, one 16B
    // GLOAD each (2 vmem/wave/tile). lane covers LDS bytes [wave*1024+lane*16]
    // = row (wave*8+(lane>>3)), slot (lane&7). Source picked so LDS slot b at
    // row r holds: K block b^(r&7); V perm-slot (b-r)&7.
    const int srow = wave * 8 + (lane >> 3);
    const int slot = lane & 7;
    const u16* kg0 = kp + srow * HDIM + (slot ^ (srow & 7)) * 8;
    const u16* vg0 = vp + (size_t)srow * T_SEQ + ((slot - srow) & 7) * 8;

    auto stage = [&](int j, int buf) {
        GLOAD_LDS16(kg0 + j * 64 * HDIM, &Kl[buf][wave * 512]);
        GLOAD_LDS16(vg0 + j * 64, &Vl[buf][wave * 512]);
    };

    // Q fragments: qf[qb][kc], lane l15 holds Q[qb*16+l15][kc*32+quad*8..+7],
    // pre-scaled by scale*log2(e). Loaded before the pipeline prologue.
    const float SL2E = 0.125f * 1.44269504088896f;
    bf16x8 qf[2][2];
    {
#pragma unroll
        for (int qb = 0; qb < 2; qb++) {
            const float* qrow = qp + (size_t)(qrow_base + qb * 16 + l15) * HDIM;
#pragma unroll
            for (int kc = 0; kc < 2; kc++) {
                const float4* p4 = (const float4*)(qrow + kc * 32 + quad * 8);
                float4 fa = p4[0], fb = p4[1];
                union { bf16x8 v; u16 s[8]; } cv;
                cv.s[0] = f2b_rne(fa.x * SL2E); cv.s[1] = f2b_rne(fa.y * SL2E);
                cv.s[2] = f2b_rne(fa.z * SL2E); cv.s[3] = f2b_rne(fa.w * SL2E);
                cv.s[4] = f2b_rne(fb.x * SL2E); cv.s[5] = f2b_rne(fb.y * SL2E);
                cv.s[6] = f2b_rne(fb.z * SL2E); cv.s[7] = f2b_rne(fb.w * SL2E);
                qf[qb][kc] = cv.v;
            }
        }
    }

    // all-ones bf16 B-frag for MFMA row-sums
    union { u16 h[8]; bf16x8 v; } onesu;
#pragma unroll
    for (int i = 0; i < 8; i++) onesu.h[i] = 0x3F80;
    const bf16x8 ones = onesu.v;

    // pipeline prologue: 3 tiles in flight (qtHi >= 16 always)
    stage(0, 0);
    stage(1, 1);
    stage(2, 2);

    floatx4 o_acc[2][4];                           // [qb][dt], partial over khalf
    floatx4 lsacc[2];                              // [qb] partial row-sums
#pragma unroll
    for (int qb = 0; qb < 2; qb++) {
        lsacc[qb] = (floatx4){0.f, 0.f, 0.f, 0.f};
#pragma unroll
        for (int dt = 0; dt < 4; dt++) o_acc[qb][dt] = (floatx4){0.f, 0.f, 0.f, 0.f};
    }

    for (int j = 0; j <= qtHi; ++j) {
        // counted waits: tile j's loads done, tiles j+1,j+2 stay in flight
        if (j + 2 <= qtHi)      WAIT_VM(4);
        else if (j + 1 <= qtHi) WAIT_VM(2);
        else                    WAIT_VM(0);
        __builtin_amdgcn_s_barrier();              // all waves' tile-j in LDS

        const int cur = j & 3;
        const bool active = (j <= qt);             // wave-uniform

        // K fragments for this wave's 32 keys (4KB): read before next stage
        bf16x8 kf[2][2];                           // [kc][kb]
        if (active) {
            const u16* Kc = Kl[cur];
#pragma unroll
            for (int kc = 0; kc < 2; kc++)
#pragma unroll
                for (int kb2 = 0; kb2 < 2; kb2++) {
                    int rk = khalf * 32 + kb2 * 16 + l15;
                    kf[kc][kb2] = *(const bf16x8*)(Kc + rk * 64 + ((kc * 4 + quad) ^ (rk & 7)) * 8);
                }
        }
        if (j + 3 <= qtHi) stage(j + 3, (j + 3) & 3);  // async prefetch, 3 ahead
        if (!active) continue;

        // S^T quadrant = K(32 own keys) . Q^T(32 own q): 8 MFMA
        floatx4 sacc[2][2];                        // [kb][qb]
#pragma unroll
        for (int kb2 = 0; kb2 < 2; kb2++)
#pragma unroll
            for (int qb = 0; qb < 2; qb++) sacc[kb2][qb] = (floatx4){0.f, 0.f, 0.f, 0.f};
        __builtin_amdgcn_s_setprio(1);
#pragma unroll
        for (int kc = 0; kc < 2; kc++)
#pragma unroll
            for (int kb2 = 0; kb2 < 2; kb2++)
#pragma unroll
                for (int qb = 0; qb < 2; qb++)
                    sacc[kb2][qb] = __builtin_amdgcn_mfma_f32_16x16x32_bf16(
                        kf[kc][kb2], qf[qb][kc], sacc[kb2][qb], 0, 0, 0);
        __builtin_amdgcn_s_setprio(0);

        // P^T = exp2(S^T); causal mask only on the diagonal tile; pack into
        // PV A-frags: element e = kb*4+rg <-> key khalf*32+kb*16+quad*4+rg
        union { bf16x8 v; u16 h[8]; } pk[2];
        if (j == qt) {
            const int key0 = khalf * 32 + quad * 4;
#pragma unroll
            for (int qb = 0; qb < 2; qb++) {
                const int gq = qhalf * 32 + qb * 16 + l15;
#pragma unroll
                for (int kb2 = 0; kb2 < 2; kb2++)
#pragma unroll
                    for (int rg = 0; rg < 4; rg++) {
                        float e = __builtin_amdgcn_exp2f(sacc[kb2][qb][rg]);
                        if (key0 + kb2 * 16 + rg > gq) e = 0.f;
                        pk[qb].h[kb2 * 4 + rg] = f2b_trunc(e);
                    }
            }
        } else {
#pragma unroll
            for (int qb = 0; qb < 2; qb++)
#pragma unroll
                for (int kb2 = 0; kb2 < 2; kb2++)
#pragma unroll
                    for (int rg = 0; rg < 4; rg++)
                        pk[qb].h[kb2 * 4 + rg] =
                            f2b_trunc(__builtin_amdgcn_exp2f(sacc[kb2][qb][rg]));
        }

        // V fragments for this wave's 32 keys (4KB), chunk tp = khalf
        const u16* Vc = Vl[cur];
        bf16x8 vf[4];
#pragma unroll
        for (int dt = 0; dt < 4; dt++) {
            int d = dt * 16 + l15;
            vf[dt] = *(const bf16x8*)(Vc + d * 64 + ((khalf * 4 + quad + d) & 7) * 8);
        }

        // O_partial += P . V (8 MFMA) ; row-sums += P . ones (2 MFMA)
        __builtin_amdgcn_s_setprio(1);
#pragma unroll
        for (int dt = 0; dt < 4; dt++)
#pragma unroll
            for (int qb = 0; qb < 2; qb++)
                o_acc[qb][dt] = __builtin_amdgcn_mfma_f32_16x16x32_bf16(
                    pk[qb].v, vf[dt], o_acc[qb][dt], 0, 0, 0);
        lsacc[0] = __builtin_amdgcn_mfma_f32_16x16x32_bf16(pk[0].v, ones, lsacc[0], 0, 0, 0);
        lsacc[1] = __builtin_amdgcn_mfma_f32_16x16x32_bf16(pk[1].v, ones, lsacc[1], 0, 0, 0);
        __builtin_amdgcn_s_setprio(0);
    }

    // ---- epilogue: khalf pair-reduce via LDS, normalize, store ----
    // lsacc[qb][rg] = partial row-sum for q = qrow_base + qb*16 + quad*4 + rg
    // (identical across l15) -- exactly o_acc's row indexing.
    __syncthreads();                               // main-loop LDS use complete
    const int r = wave >> 1;                       // pair region 0..3
    float* xch = ((r & 2) ? (float*)&Vl[0][0] : (float*)&Kl[0][0]) + (r & 1) * 2560;
    floatx4* xv = (floatx4*)xch;                   // [plane 0..9][lane] 16B, conflict-free
    if (khalf == 0) {
#pragma unroll
        for (int qb = 0; qb < 2; qb++)
#pragma unroll
            for (int dt = 0; dt < 4; dt++) xv[(qb * 4 + dt) * 64 + lane] = o_acc[qb][dt];
        xv[8 * 64 + lane] = lsacc[0];
        xv[9 * 64 + lane] = lsacc[1];
    }
    __syncthreads();
    if (khalf == 1) {
#pragma unroll
        for (int qb = 0; qb < 2; qb++) {
#pragma unroll
            for (int dt = 0; dt < 4; dt++) o_acc[qb][dt] += xv[(qb * 4 + dt) * 64 + lane];
            lsacc[qb] += xv[(8 + qb) * 64 + lane];
        }
        float* op = out + (size_t)bh * T_SEQ * HDIM;
#pragma unroll
        for (int qb = 0; qb < 2; qb++)
#pragma unroll
            for (int rg = 0; rg < 4; rg++) {
                float inv = 1.0f / lsacc[qb][rg];
                size_t row = (size_t)(qrow_base + qb * 16 + quad * 4 + rg) * HDIM;
#pragma unroll
                for (int dt = 0; dt < 4; dt++)
                    op[row + dt * 16 + l15] = o_acc[qb][dt][rg] * inv;
            }
    }
}

extern "C" void kernel_launch(void* const* d_in, const int* in_sizes, int n_in,
                              void* d_out, int out_size, void* d_ws, size_t ws_size,
                              hipStream_t stream) {
    const float* q = (const float*)d_in[0];
    const float* k = (const float*)d_in[1];
    const float* v = (const float*)d_in[2];
    float* out = (float*)d_out;

    u16* kb = (u16*)d_ws;                               // 8 MB bf16 K
    u16* vt = kb + (size_t)NBH * T_SEQ * HDIM;          // 8 MB bf16 V^T (permuted)

    prep<<<dim3(T_SEQ / 64, NBH), 256, 0, stream>>>(k, v, kb, vt);
    fattn<<<dim3(512), 512, 0, stream>>>(q, kb, vt, out);
}